// Round 7
// baseline (139.518 us; speedup 1.0000x reference)
//
#include <hip/hip_runtime.h>
#include <math.h>

#define NB 64
#define NT 2048
#define NH 512
#define NOUT 128
#define TCH 32          // t-chunks (blocks per batch) for flash pass
#define TPC 64          // timesteps per chunk (NT/TCH)
#define RPW 16          // rows per wave (TPC / 4 waves)

// ---------------------------------------------------------------------------
// K1: v[b,h] = sum_k W_score[h,k] * h_t[b,k]   (h_t = hidden[b, T-1, :])
// grid (NB, 4), 256 threads: 128 h-values per block, k split 2-way.
// ---------------------------------------------------------------------------
__global__ __launch_bounds__(256) void k_v(const float* __restrict__ hidden,
                                           const float* __restrict__ Wscore,
                                           float* __restrict__ v) {
    __shared__ float ht[NH];
    __shared__ float red[128];
    const int b = blockIdx.x;
    const float* hrow = hidden + ((size_t)b * NT + (NT - 1)) * NH;
    for (int k = threadIdx.x; k < NH; k += 256) ht[k] = hrow[k];
    __syncthreads();
    const int h = blockIdx.y * 128 + (threadIdx.x & 127);
    const int half = threadIdx.x >> 7;  // 0/1: k-slice
    const float4* wr =
        reinterpret_cast<const float4*>(Wscore + (size_t)h * NH) + half * 64;
    const float* hts = ht + half * 256;
    float acc = 0.f;
#pragma unroll 16
    for (int k4 = 0; k4 < 64; ++k4) {
        float4 w = wr[k4];
        acc += w.x * hts[k4 * 4 + 0] + w.y * hts[k4 * 4 + 1] +
               w.z * hts[k4 * 4 + 2] + w.w * hts[k4 * 4 + 3];
    }
    if (half) red[threadIdx.x & 127] = acc;
    __syncthreads();
    if (!half) v[(size_t)b * NH + h] = acc + red[threadIdx.x];
}

// ---------------------------------------------------------------------------
// K2 (flash): one pass over hidden. Per (b, chunk): each wave owns 16 rows,
// processed in PAIRS: two independent dots + two interleaved shfl butterflies
// (ILP on the reduce latency), then ONE online-softmax update per pair
// (halves the serial m/l/c dependency chain). Double-buffered pair prefetch:
// pair rp+1's 4 float4 loads are in flight while pair rp is consumed.
// Plain cacheable loads — L3 retains a large fraction of `hidden` across
// graph replays (nt loads measurably regressed, round 6).
// ---------------------------------------------------------------------------
__global__ __launch_bounds__(256, 8) void k_flash(const float* __restrict__ hidden,
                                                  const float* __restrict__ v,
                                                  float* __restrict__ pctx,
                                                  float* __restrict__ pm,
                                                  float* __restrict__ pl) {
    const int b = blockIdx.x / TCH;
    const int tc = blockIdx.x % TCH;
    const int wid = threadIdx.x >> 6;
    const int lane = threadIdx.x & 63;

    const float4* vb = reinterpret_cast<const float4*>(v + (size_t)b * NH);
    const float4 v0 = vb[lane];
    const float4 v1 = vb[64 + lane];

    const float4* hbase = reinterpret_cast<const float4*>(
        hidden + ((size_t)b * NT + tc * TPC + wid * RPW) * NH);

    float4 c0 = {0.f, 0.f, 0.f, 0.f}, c1 = {0.f, 0.f, 0.f, 0.f};
    float m = -INFINITY, l = 0.f;

    // prologue: pairs 0 (X) and 1 (Y) in flight
    float4 XA0 = hbase[lane],       XA1 = hbase[64 + lane];
    float4 XB0 = hbase[128 + lane], XB1 = hbase[128 + 64 + lane];
    float4 YA0 = hbase[256 + lane], YA1 = hbase[256 + 64 + lane];
    float4 YB0 = hbase[384 + lane], YB1 = hbase[384 + 64 + lane];

#pragma unroll
    for (int rp = 0; rp < RPW / 2; ++rp) {
        float4 hA0, hA1, hB0, hB1;
        if (rp & 1) { hA0 = YA0; hA1 = YA1; hB0 = YB0; hB1 = YB1; }
        else        { hA0 = XA0; hA1 = XA1; hB0 = XB0; hB1 = XB1; }
        if (rp + 2 < RPW / 2) {  // refill the buffer just consumed with pair rp+2
            const float4* p = hbase + (size_t)(rp + 2) * 256;
            if (rp & 1) {
                YA0 = p[lane]; YA1 = p[64 + lane];
                YB0 = p[128 + lane]; YB1 = p[128 + 64 + lane];
            } else {
                XA0 = p[lane]; XA1 = p[64 + lane];
                XB0 = p[128 + lane]; XB1 = p[128 + 64 + lane];
            }
        }
        float sA = hA0.x * v0.x + hA0.y * v0.y + hA0.z * v0.z + hA0.w * v0.w +
                   hA1.x * v1.x + hA1.y * v1.y + hA1.z * v1.z + hA1.w * v1.w;
        float sB = hB0.x * v0.x + hB0.y * v0.y + hB0.z * v0.z + hB0.w * v0.w +
                   hB1.x * v1.x + hB1.y * v1.y + hB1.z * v1.z + hB1.w * v1.w;
#pragma unroll
        for (int off = 32; off >= 1; off >>= 1) {  // two butterflies, interleaved
            sA += __shfl_xor(sA, off, 64);
            sB += __shfl_xor(sB, off, 64);
        }
        const float mn = fmaxf(m, fmaxf(sA, sB));  // -> v_max3
        if (mn > m) {  // wave-uniform; one rescale per PAIR
            float sc = __expf(m - mn);
            c0.x *= sc; c0.y *= sc; c0.z *= sc; c0.w *= sc;
            c1.x *= sc; c1.y *= sc; c1.z *= sc; c1.w *= sc;
            l *= sc;
            m = mn;
        }
        const float pA = __expf(sA - m), pB = __expf(sB - m);
        l += pA + pB;
        c0.x += pA * hA0.x + pB * hB0.x; c0.y += pA * hA0.y + pB * hB0.y;
        c0.z += pA * hA0.z + pB * hB0.z; c0.w += pA * hA0.w + pB * hB0.w;
        c1.x += pA * hA1.x + pB * hB1.x; c1.y += pA * hA1.y + pB * hB1.y;
        c1.z += pA * hA1.z + pB * hB1.z; c1.w += pA * hA1.w + pB * hB1.w;
    }

    // cross-wave combine
    __shared__ float cl[4][NH];
    __shared__ float ml[4], ll[4];
    reinterpret_cast<float4*>(cl[wid])[lane] = c0;
    reinterpret_cast<float4*>(cl[wid])[64 + lane] = c1;
    if (lane == 0) { ml[wid] = m; ll[wid] = l; }
    __syncthreads();

    const float mb = fmaxf(fmaxf(ml[0], ml[1]), fmaxf(ml[2], ml[3]));
    const float e0 = __expf(ml[0] - mb), e1 = __expf(ml[1] - mb);
    const float e2 = __expf(ml[2] - mb), e3 = __expf(ml[3] - mb);

    const int h2 = threadIdx.x;  // float2 column, 0..255
    float2 a;
    a.x = cl[0][2 * h2] * e0 + cl[1][2 * h2] * e1 +
          cl[2][2 * h2] * e2 + cl[3][2 * h2] * e3;
    a.y = cl[0][2 * h2 + 1] * e0 + cl[1][2 * h2 + 1] * e1 +
          cl[2][2 * h2 + 1] * e2 + cl[3][2 * h2 + 1] * e3;
    reinterpret_cast<float2*>(pctx + ((size_t)b * TCH + tc) * NH)[h2] = a;
    if (threadIdx.x == 0) {
        pm[b * TCH + tc] = mb;
        pl[b * TCH + tc] = ll[0] * e0 + ll[1] * e1 + ll[2] * e2 + ll[3] * e3;
    }
}

// ---------------------------------------------------------------------------
// K3: combine chunk partials -> context, concat h_t, GEMV W_out, tanh.
// grid (NB, 2): each block does 64 of the 128 outputs, j-range split 4-way.
// ---------------------------------------------------------------------------
__global__ __launch_bounds__(256) void k_out(const float* __restrict__ hidden,
                                             const float* __restrict__ pctx,
                                             const float* __restrict__ pm,
                                             const float* __restrict__ pl,
                                             const float* __restrict__ Wout,
                                             float* __restrict__ out) {
    __shared__ float pre[2 * NH];
    __shared__ float red[4][64];
    const int b = blockIdx.x;

    // global max / denom across chunks (redundant per thread; L2-resident)
    float Mb = -INFINITY;
#pragma unroll
    for (int t = 0; t < TCH; ++t) Mb = fmaxf(Mb, pm[b * TCH + t]);
    float Lb = 0.f;
#pragma unroll
    for (int t = 0; t < TCH; ++t)
        Lb += pl[b * TCH + t] * __expf(pm[b * TCH + t] - Mb);
    const float invL = 1.f / Lb;

    // combine context; thread owns one float2 column
    const int h2 = threadIdx.x;
    float2 a = {0.f, 0.f};
#pragma unroll 4
    for (int t = 0; t < TCH; ++t) {
        float e = __expf(pm[b * TCH + t] - Mb);
        float2 p =
            reinterpret_cast<const float2*>(pctx + ((size_t)b * TCH + t) * NH)[h2];
        a.x += e * p.x;
        a.y += e * p.y;
    }
    pre[2 * h2] = a.x * invL;
    pre[2 * h2 + 1] = a.y * invL;

    const float* hrow = hidden + ((size_t)b * NT + (NT - 1)) * NH;
    float2 hh = reinterpret_cast<const float2*>(hrow)[h2];
    pre[NH + 2 * h2] = hh.x;
    pre[NH + 2 * h2 + 1] = hh.y;
    __syncthreads();

    // GEMV: this block's 64 outputs; 4 threads per output split the j-range
    const int o = blockIdx.y * 64 + (threadIdx.x & 63);
    const int js = threadIdx.x >> 6;  // 0..3
    const int j0 = js * 256;
    float a0 = 0.f, a1 = 0.f;
#pragma unroll 8
    for (int j = j0; j < j0 + 256; j += 2) {
        a0 += pre[j] * Wout[(size_t)j * NOUT + o];
        a1 += pre[j + 1] * Wout[(size_t)(j + 1) * NOUT + o];
    }
    red[js][threadIdx.x & 63] = a0 + a1;
    __syncthreads();
    if (threadIdx.x < 64) {
        int oo = blockIdx.y * 64 + threadIdx.x;
        out[(size_t)b * NOUT + oo] =
            tanhf(red[0][threadIdx.x] + red[1][threadIdx.x] +
                  red[2][threadIdx.x] + red[3][threadIdx.x]);
    }
}

// ---------------------------------------------------------------------------
extern "C" void kernel_launch(void* const* d_in, const int* in_sizes, int n_in,
                              void* d_out, int out_size, void* d_ws, size_t ws_size,
                              hipStream_t stream) {
    const float* hidden = (const float*)d_in[0];  // (B,T,H)
    const float* Wscore = (const float*)d_in[1];  // (H,H)
    const float* Wout = (const float*)d_in[2];    // (2H,OUT)
    float* out = (float*)d_out;                   // (B,OUT) fp32

    float* ws = (float*)d_ws;
    float* v = ws;                               // NB*NH
    float* pctx = v + NB * NH;                   // NB*TCH*NH
    float* pm = pctx + (size_t)NB * TCH * NH;    // NB*TCH
    float* pl = pm + NB * TCH;                   // NB*TCH

    k_v<<<dim3(NB, 4), 256, 0, stream>>>(hidden, Wscore, v);
    k_flash<<<NB * TCH, 256, 0, stream>>>(hidden, v, pctx, pm, pl);
    k_out<<<dim3(NB, 2), 256, 0, stream>>>(hidden, pctx, pm, pl, Wout, out);
}

// Round 8
// 72.706 us; speedup vs baseline: 1.9189x; 1.9189x over previous
//
#include <hip/hip_runtime.h>
#include <math.h>

#define NB 64
#define NT 2048
#define NH 512
#define NOUT 128
#define TCH 64          // t-chunks (blocks per batch) for flash pass
#define TPC 32          // timesteps per chunk (NT/TCH)
#define RPW 8           // rows per wave (TPC / 4 waves)

// ---------------------------------------------------------------------------
// K1: v[b,h] = sum_k W_score[h,k] * h_t[b,k]   (h_t = hidden[b, T-1, :])
// grid (NB, 4), 256 threads: 128 h-values per block, k split 2-way.
// ---------------------------------------------------------------------------
__global__ __launch_bounds__(256) void k_v(const float* __restrict__ hidden,
                                           const float* __restrict__ Wscore,
                                           float* __restrict__ v) {
    __shared__ float ht[NH];
    __shared__ float red[128];
    const int b = blockIdx.x;
    const float* hrow = hidden + ((size_t)b * NT + (NT - 1)) * NH;
    for (int k = threadIdx.x; k < NH; k += 256) ht[k] = hrow[k];
    __syncthreads();
    const int h = blockIdx.y * 128 + (threadIdx.x & 127);
    const int half = threadIdx.x >> 7;  // 0/1: k-slice
    const float4* wr =
        reinterpret_cast<const float4*>(Wscore + (size_t)h * NH) + half * 64;
    const float* hts = ht + half * 256;
    float acc = 0.f;
#pragma unroll 16
    for (int k4 = 0; k4 < 64; ++k4) {
        float4 w = wr[k4];
        acc += w.x * hts[k4 * 4 + 0] + w.y * hts[k4 * 4 + 1] +
               w.z * hts[k4 * 4 + 2] + w.w * hts[k4 * 4 + 3];
    }
    if (half) red[threadIdx.x & 127] = acc;
    __syncthreads();
    if (!half) v[(size_t)b * NH + h] = acc + red[threadIdx.x];
}

// ---------------------------------------------------------------------------
// K2 (flash): one pass over hidden. Per (b, chunk): each wave owns 8 rows;
// per row, read the 512-float row ONCE, use it for the score dot AND the
// online-softmax-weighted context accumulation. Register double-buffer:
// row r+1's two float4 loads are issued before row r is consumed (+8 VGPR,
// stays under the 64-VGPR / 8-waves-per-SIMD cliff — deeper pipelines spill,
// round 7). TCH=64 halves each wave's serial softmax chain vs TCH=32.
// Cacheable loads: L3 retains part of `hidden` across replays (nt regressed).
// ---------------------------------------------------------------------------
__global__ __launch_bounds__(256, 8) void k_flash(const float* __restrict__ hidden,
                                                  const float* __restrict__ v,
                                                  float* __restrict__ pctx,
                                                  float* __restrict__ pm,
                                                  float* __restrict__ pl) {
    const int b = blockIdx.x / TCH;
    const int tc = blockIdx.x % TCH;
    const int wid = threadIdx.x >> 6;
    const int lane = threadIdx.x & 63;

    const float4* vb = reinterpret_cast<const float4*>(v + (size_t)b * NH);
    const float4 v0 = vb[lane];
    const float4 v1 = vb[64 + lane];

    const float4* hbase = reinterpret_cast<const float4*>(
        hidden + ((size_t)b * NT + tc * TPC + wid * RPW) * NH);

    float4 c0 = {0.f, 0.f, 0.f, 0.f}, c1 = {0.f, 0.f, 0.f, 0.f};
    float m = -INFINITY, l = 0.f;

    // prefetch row 0
    float4 a0 = hbase[lane];
    float4 a1 = hbase[64 + lane];

#pragma unroll
    for (int r = 0; r < RPW; ++r) {
        float4 h0 = a0, h1 = a1;
        if (r + 1 < RPW) {  // issue next row's loads before consuming current
            a0 = hbase[(size_t)(r + 1) * 128 + lane];
            a1 = hbase[(size_t)(r + 1) * 128 + 64 + lane];
        }
        float s = h0.x * v0.x + h0.y * v0.y + h0.z * v0.z + h0.w * v0.w +
                  h1.x * v1.x + h1.y * v1.y + h1.z * v1.z + h1.w * v1.w;
#pragma unroll
        for (int off = 32; off >= 1; off >>= 1) s += __shfl_xor(s, off, 64);
        // wave-uniform online softmax update
        if (s > m) {
            float sc = __expf(m - s);
            c0.x *= sc; c0.y *= sc; c0.z *= sc; c0.w *= sc;
            c1.x *= sc; c1.y *= sc; c1.z *= sc; c1.w *= sc;
            l *= sc;
            m = s;
        }
        float p = __expf(s - m);
        l += p;
        c0.x += p * h0.x; c0.y += p * h0.y; c0.z += p * h0.z; c0.w += p * h0.w;
        c1.x += p * h1.x; c1.y += p * h1.y; c1.z += p * h1.z; c1.w += p * h1.w;
    }

    // cross-wave combine
    __shared__ float cl[4][NH];
    __shared__ float ml[4], ll[4];
    reinterpret_cast<float4*>(cl[wid])[lane] = c0;
    reinterpret_cast<float4*>(cl[wid])[64 + lane] = c1;
    if (lane == 0) { ml[wid] = m; ll[wid] = l; }
    __syncthreads();

    const float mb = fmaxf(fmaxf(ml[0], ml[1]), fmaxf(ml[2], ml[3]));
    const float e0 = __expf(ml[0] - mb), e1 = __expf(ml[1] - mb);
    const float e2 = __expf(ml[2] - mb), e3 = __expf(ml[3] - mb);

    const int h2 = threadIdx.x;  // float2 column, 0..255
    float2 a;
    a.x = cl[0][2 * h2] * e0 + cl[1][2 * h2] * e1 +
          cl[2][2 * h2] * e2 + cl[3][2 * h2] * e3;
    a.y = cl[0][2 * h2 + 1] * e0 + cl[1][2 * h2 + 1] * e1 +
          cl[2][2 * h2 + 1] * e2 + cl[3][2 * h2 + 1] * e3;
    reinterpret_cast<float2*>(pctx + ((size_t)b * TCH + tc) * NH)[h2] = a;
    if (threadIdx.x == 0) {
        pm[b * TCH + tc] = mb;
        pl[b * TCH + tc] = ll[0] * e0 + ll[1] * e1 + ll[2] * e2 + ll[3] * e3;
    }
}

// ---------------------------------------------------------------------------
// K3: combine chunk partials -> context, concat h_t, GEMV W_out, tanh.
// grid (NB, 2): each block does 64 of the 128 outputs, j-range split 4-way.
// ---------------------------------------------------------------------------
__global__ __launch_bounds__(256) void k_out(const float* __restrict__ hidden,
                                             const float* __restrict__ pctx,
                                             const float* __restrict__ pm,
                                             const float* __restrict__ pl,
                                             const float* __restrict__ Wout,
                                             float* __restrict__ out) {
    __shared__ float pre[2 * NH];
    __shared__ float red[4][64];
    const int b = blockIdx.x;

    // global max / denom across chunks (redundant per thread; L2-resident)
    float Mb = -INFINITY;
#pragma unroll 8
    for (int t = 0; t < TCH; ++t) Mb = fmaxf(Mb, pm[b * TCH + t]);
    float Lb = 0.f;
#pragma unroll 8
    for (int t = 0; t < TCH; ++t)
        Lb += pl[b * TCH + t] * __expf(pm[b * TCH + t] - Mb);
    const float invL = 1.f / Lb;

    // combine context; thread owns one float2 column
    const int h2 = threadIdx.x;
    float2 a = {0.f, 0.f};
#pragma unroll 4
    for (int t = 0; t < TCH; ++t) {
        float e = __expf(pm[b * TCH + t] - Mb);
        float2 p =
            reinterpret_cast<const float2*>(pctx + ((size_t)b * TCH + t) * NH)[h2];
        a.x += e * p.x;
        a.y += e * p.y;
    }
    pre[2 * h2] = a.x * invL;
    pre[2 * h2 + 1] = a.y * invL;

    const float* hrow = hidden + ((size_t)b * NT + (NT - 1)) * NH;
    float2 hh = reinterpret_cast<const float2*>(hrow)[h2];
    pre[NH + 2 * h2] = hh.x;
    pre[NH + 2 * h2 + 1] = hh.y;
    __syncthreads();

    // GEMV: this block's 64 outputs; 4 threads per output split the j-range
    const int o = blockIdx.y * 64 + (threadIdx.x & 63);
    const int js = threadIdx.x >> 6;  // 0..3
    const int j0 = js * 256;
    float a0 = 0.f, a1 = 0.f;
#pragma unroll 8
    for (int j = j0; j < j0 + 256; j += 2) {
        a0 += pre[j] * Wout[(size_t)j * NOUT + o];
        a1 += pre[j + 1] * Wout[(size_t)(j + 1) * NOUT + o];
    }
    red[js][threadIdx.x & 63] = a0 + a1;
    __syncthreads();
    if (threadIdx.x < 64) {
        int oo = blockIdx.y * 64 + threadIdx.x;
        out[(size_t)b * NOUT + oo] =
            tanhf(red[0][threadIdx.x] + red[1][threadIdx.x] +
                  red[2][threadIdx.x] + red[3][threadIdx.x]);
    }
}

// ---------------------------------------------------------------------------
extern "C" void kernel_launch(void* const* d_in, const int* in_sizes, int n_in,
                              void* d_out, int out_size, void* d_ws, size_t ws_size,
                              hipStream_t stream) {
    const float* hidden = (const float*)d_in[0];  // (B,T,H)
    const float* Wscore = (const float*)d_in[1];  // (H,H)
    const float* Wout = (const float*)d_in[2];    // (2H,OUT)
    float* out = (float*)d_out;                   // (B,OUT) fp32

    float* ws = (float*)d_ws;
    float* v = ws;                               // NB*NH
    float* pctx = v + NB * NH;                   // NB*TCH*NH
    float* pm = pctx + (size_t)NB * TCH * NH;    // NB*TCH
    float* pl = pm + NB * TCH;                   // NB*TCH

    k_v<<<dim3(NB, 4), 256, 0, stream>>>(hidden, Wscore, v);
    k_flash<<<NB * TCH, 256, 0, stream>>>(hidden, v, pctx, pm, pl);
    k_out<<<dim3(NB, 2), 256, 0, stream>>>(hidden, pctx, pm, pl, Wout, out);
}

// Round 9
// 64.565 us; speedup vs baseline: 2.1609x; 1.1261x over previous
//
#include <hip/hip_runtime.h>
#include <math.h>

#define NB 64
#define NT 2048
#define NH 512
#define NOUT 128
#define TCH 32          // t-chunks (blocks per batch) — 32 optimal (64: +8us r8; 16 under-occupies)
#define TPC 64          // timesteps per chunk (NT/TCH)
#define RPW 16          // rows per wave (TPC / 4 waves)

// ---------------------------------------------------------------------------
// K1: v[b,h] = sum_k W_score[h,k] * h_t[b,k]   (h_t = hidden[b, T-1, :])
// grid (NB, 4), 256 threads: 128 h-values per block, k split 2-way.
// ---------------------------------------------------------------------------
__global__ __launch_bounds__(256) void k_v(const float* __restrict__ hidden,
                                           const float* __restrict__ Wscore,
                                           float* __restrict__ v) {
    __shared__ float ht[NH];
    __shared__ float red[128];
    const int b = blockIdx.x;
    const float* hrow = hidden + ((size_t)b * NT + (NT - 1)) * NH;
    for (int k = threadIdx.x; k < NH; k += 256) ht[k] = hrow[k];
    __syncthreads();
    const int h = blockIdx.y * 128 + (threadIdx.x & 127);
    const int half = threadIdx.x >> 7;  // 0/1: k-slice
    const float4* wr =
        reinterpret_cast<const float4*>(Wscore + (size_t)h * NH) + half * 64;
    const float* hts = ht + half * 256;
    float acc = 0.f;
#pragma unroll 16
    for (int k4 = 0; k4 < 64; ++k4) {
        float4 w = wr[k4];
        acc += w.x * hts[k4 * 4 + 0] + w.y * hts[k4 * 4 + 1] +
               w.z * hts[k4 * 4 + 2] + w.w * hts[k4 * 4 + 3];
    }
    if (half) red[threadIdx.x & 127] = acc;
    __syncthreads();
    if (!half) v[(size_t)b * NH + h] = acc + red[threadIdx.x];
}

// ---------------------------------------------------------------------------
// K2 (flash): one pass over hidden. Per (b, chunk): each wave owns 16 rows;
// per row, read the 512-float row ONCE, use it for the score dot AND the
// online-softmax-weighted context accumulation. Register double-buffer:
// row r+1's two float4 loads in flight while row r is consumed (2-deep is
// the VGPR sweet spot: 3-deep spills past the 64-VGPR/8-wave cliff, r7).
// Cacheable loads: L3 retains ~half of hidden across replays (nt lost it, r6).
// ---------------------------------------------------------------------------
__global__ __launch_bounds__(256, 8) void k_flash(const float* __restrict__ hidden,
                                                  const float* __restrict__ v,
                                                  float* __restrict__ pctx,
                                                  float* __restrict__ pm,
                                                  float* __restrict__ pl) {
    const int b = blockIdx.x / TCH;
    const int tc = blockIdx.x % TCH;
    const int wid = threadIdx.x >> 6;
    const int lane = threadIdx.x & 63;

    const float4* vb = reinterpret_cast<const float4*>(v + (size_t)b * NH);
    const float4 v0 = vb[lane];
    const float4 v1 = vb[64 + lane];

    const float4* hbase = reinterpret_cast<const float4*>(
        hidden + ((size_t)b * NT + tc * TPC + wid * RPW) * NH);

    float4 c0 = {0.f, 0.f, 0.f, 0.f}, c1 = {0.f, 0.f, 0.f, 0.f};
    float m = -INFINITY, l = 0.f;

    // prefetch row 0
    float4 a0 = hbase[lane];
    float4 a1 = hbase[64 + lane];

#pragma unroll
    for (int r = 0; r < RPW; ++r) {
        float4 h0 = a0, h1 = a1;
        if (r + 1 < RPW) {  // issue next row's loads before consuming current
            a0 = hbase[(size_t)(r + 1) * 128 + lane];
            a1 = hbase[(size_t)(r + 1) * 128 + 64 + lane];
        }
        float s = h0.x * v0.x + h0.y * v0.y + h0.z * v0.z + h0.w * v0.w +
                  h1.x * v1.x + h1.y * v1.y + h1.z * v1.z + h1.w * v1.w;
#pragma unroll
        for (int off = 32; off >= 1; off >>= 1) s += __shfl_xor(s, off, 64);
        // wave-uniform online softmax update
        if (s > m) {
            float sc = __expf(m - s);
            c0.x *= sc; c0.y *= sc; c0.z *= sc; c0.w *= sc;
            c1.x *= sc; c1.y *= sc; c1.z *= sc; c1.w *= sc;
            l *= sc;
            m = s;
        }
        float p = __expf(s - m);
        l += p;
        c0.x += p * h0.x; c0.y += p * h0.y; c0.z += p * h0.z; c0.w += p * h0.w;
        c1.x += p * h1.x; c1.y += p * h1.y; c1.z += p * h1.z; c1.w += p * h1.w;
    }

    // cross-wave combine
    __shared__ float cl[4][NH];
    __shared__ float ml[4], ll[4];
    reinterpret_cast<float4*>(cl[wid])[lane] = c0;
    reinterpret_cast<float4*>(cl[wid])[64 + lane] = c1;
    if (lane == 0) { ml[wid] = m; ll[wid] = l; }
    __syncthreads();

    const float mb = fmaxf(fmaxf(ml[0], ml[1]), fmaxf(ml[2], ml[3]));
    const float e0 = __expf(ml[0] - mb), e1 = __expf(ml[1] - mb);
    const float e2 = __expf(ml[2] - mb), e3 = __expf(ml[3] - mb);

    const int h2 = threadIdx.x;  // float2 column, 0..255
    float2 a;
    a.x = cl[0][2 * h2] * e0 + cl[1][2 * h2] * e1 +
          cl[2][2 * h2] * e2 + cl[3][2 * h2] * e3;
    a.y = cl[0][2 * h2 + 1] * e0 + cl[1][2 * h2 + 1] * e1 +
          cl[2][2 * h2 + 1] * e2 + cl[3][2 * h2 + 1] * e3;
    reinterpret_cast<float2*>(pctx + ((size_t)b * TCH + tc) * NH)[h2] = a;
    if (threadIdx.x == 0) {
        pm[b * TCH + tc] = mb;
        pl[b * TCH + tc] = ll[0] * e0 + ll[1] * e1 + ll[2] * e2 + ll[3] * e3;
    }
}

// ---------------------------------------------------------------------------
// K3: combine chunk partials -> context, concat h_t, GEMV W_out, tanh.
// grid (NB, 2): each block does 64 of the 128 outputs, j-range split 4-way.
// ---------------------------------------------------------------------------
__global__ __launch_bounds__(256) void k_out(const float* __restrict__ hidden,
                                             const float* __restrict__ pctx,
                                             const float* __restrict__ pm,
                                             const float* __restrict__ pl,
                                             const float* __restrict__ Wout,
                                             float* __restrict__ out) {
    __shared__ float pre[2 * NH];
    __shared__ float red[4][64];
    const int b = blockIdx.x;

    // global max / denom across chunks (redundant per thread; L2-resident)
    float Mb = -INFINITY;
#pragma unroll
    for (int t = 0; t < TCH; ++t) Mb = fmaxf(Mb, pm[b * TCH + t]);
    float Lb = 0.f;
#pragma unroll
    for (int t = 0; t < TCH; ++t)
        Lb += pl[b * TCH + t] * __expf(pm[b * TCH + t] - Mb);
    const float invL = 1.f / Lb;

    // combine context; thread owns one float2 column
    const int h2 = threadIdx.x;
    float2 a = {0.f, 0.f};
#pragma unroll 4
    for (int t = 0; t < TCH; ++t) {
        float e = __expf(pm[b * TCH + t] - Mb);
        float2 p =
            reinterpret_cast<const float2*>(pctx + ((size_t)b * TCH + t) * NH)[h2];
        a.x += e * p.x;
        a.y += e * p.y;
    }
    pre[2 * h2] = a.x * invL;
    pre[2 * h2 + 1] = a.y * invL;

    const float* hrow = hidden + ((size_t)b * NT + (NT - 1)) * NH;
    float2 hh = reinterpret_cast<const float2*>(hrow)[h2];
    pre[NH + 2 * h2] = hh.x;
    pre[NH + 2 * h2 + 1] = hh.y;
    __syncthreads();

    // GEMV: this block's 64 outputs; 4 threads per output split the j-range
    const int o = blockIdx.y * 64 + (threadIdx.x & 63);
    const int js = threadIdx.x >> 6;  // 0..3
    const int j0 = js * 256;
    float a0 = 0.f, a1 = 0.f;
#pragma unroll 8
    for (int j = j0; j < j0 + 256; j += 2) {
        a0 += pre[j] * Wout[(size_t)j * NOUT + o];
        a1 += pre[j + 1] * Wout[(size_t)(j + 1) * NOUT + o];
    }
    red[js][threadIdx.x & 63] = a0 + a1;
    __syncthreads();
    if (threadIdx.x < 64) {
        int oo = blockIdx.y * 64 + threadIdx.x;
        out[(size_t)b * NOUT + oo] =
            tanhf(red[0][threadIdx.x] + red[1][threadIdx.x] +
                  red[2][threadIdx.x] + red[3][threadIdx.x]);
    }
}

// ---------------------------------------------------------------------------
extern "C" void kernel_launch(void* const* d_in, const int* in_sizes, int n_in,
                              void* d_out, int out_size, void* d_ws, size_t ws_size,
                              hipStream_t stream) {
    const float* hidden = (const float*)d_in[0];  // (B,T,H)
    const float* Wscore = (const float*)d_in[1];  // (H,H)
    const float* Wout = (const float*)d_in[2];    // (2H,OUT)
    float* out = (float*)d_out;                   // (B,OUT) fp32

    float* ws = (float*)d_ws;
    float* v = ws;                               // NB*NH
    float* pctx = v + NB * NH;                   // NB*TCH*NH
    float* pm = pctx + (size_t)NB * TCH * NH;    // NB*TCH
    float* pl = pm + NB * TCH;                   // NB*TCH

    k_v<<<dim3(NB, 4), 256, 0, stream>>>(hidden, Wscore, v);
    k_flash<<<NB * TCH, 256, 0, stream>>>(hidden, v, pctx, pm, pl);
    k_out<<<dim3(NB, 2), 256, 0, stream>>>(hidden, pctx, pm, pl, Wout, out);
}